// Round 1
// baseline (757.776 us; speedup 1.0000x reference)
//
#include <hip/hip_runtime.h>
#include <math.h>

#define BS 32
#define NQ 900
#define NC 1203
#define NT 100

// ---------------------------------------------------------------------------
// Kernel 1: cost matrix. One block per (b,q), threads 0..99 cover targets.
// C[b][q][t] = 5*L1(bbox) + 2*(focal_pos - focal_neg) + 2*(-GIoU)
// ---------------------------------------------------------------------------
__global__ __launch_bounds__(128) void cost_kernel(
    const float* __restrict__ logits, const float* __restrict__ boxes,
    const int* __restrict__ tlabels, const float* __restrict__ tboxes,
    float* __restrict__ C)
{
    int bq = blockIdx.x;
    int b = bq / NQ, q = bq % NQ;
    int t = threadIdx.x;

    const float* pb = boxes + (size_t)(b * NQ + q) * 4;
    float pcx = pb[0], pcy = pb[1], pw = pb[2], ph = pb[3];

    if (t < NT) {
        int id = tlabels[b * NT + t];
        float x = logits[(size_t)(b * NQ + q) * NC + id];
        float prob = 1.0f / (1.0f + expf(-x));
        float neg = 0.75f * (prob * prob) * (-logf(1.0f - prob + 1e-8f));
        float pos = 0.25f * ((1.0f - prob) * (1.0f - prob)) * (-logf(prob + 1e-8f));
        float cclass = pos - neg;

        const float* tb = tboxes + (size_t)(b * NT + t) * 4;
        float tcx = tb[0], tcy = tb[1], tw = tb[2], th = tb[3];
        float cbbox = fabsf(pcx - tcx) + fabsf(pcy - tcy) + fabsf(pw - tw) + fabsf(ph - th);

        // cxcywh -> xyxy (compute areas from xyxy diffs to match reference rounding)
        float p0 = pcx - 0.5f * pw, p1 = pcy - 0.5f * ph;
        float p2 = pcx + 0.5f * pw, p3 = pcy + 0.5f * ph;
        float t0 = tcx - 0.5f * tw, t1 = tcy - 0.5f * th;
        float t2 = tcx + 0.5f * tw, t3 = tcy + 0.5f * th;
        float area1 = (p2 - p0) * (p3 - p1);
        float area2 = (t2 - t0) * (t3 - t1);
        float ltx = fmaxf(p0, t0), lty = fmaxf(p1, t1);
        float rbx = fminf(p2, t2), rby = fminf(p3, t3);
        float wx = fmaxf(rbx - ltx, 0.0f), wy = fmaxf(rby - lty, 0.0f);
        float inter = wx * wy;
        float uni = area1 + area2 - inter;
        float iou = inter / uni;
        float l2x = fminf(p0, t0), l2y = fminf(p1, t1);
        float r2x = fmaxf(p2, t2), r2y = fmaxf(p3, t3);
        float hx = fmaxf(r2x - l2x, 0.0f), hy = fmaxf(r2y - l2y, 0.0f);
        float hull = hx * hy;
        float giou = iou - (hull - uni) / hull;

        C[(size_t)(b * NQ + q) * NT + t] = 5.0f * cbbox + 2.0f * cclass + 2.0f * (-giou);
    }
}

// ---------------------------------------------------------------------------
// Kernel 2: Jonker-Volgenant LSA on C[b].T (n=100 rows, m=900 cols), one
// workgroup (single wave of 64) per batch. Doubles for duals to replicate the
// numpy float64 reference bit-exactly. Tie-break: np.argmin = smallest index.
// ---------------------------------------------------------------------------
__global__ __launch_bounds__(64) void jv_kernel(
    const float* __restrict__ C, float* __restrict__ pred_out,
    float* __restrict__ tgt_out)
{
    int b = blockIdx.x;
    const float* Cb = C + (size_t)b * NQ * NT;   // C[b][q][t]; cost.T[i][j] = Cb[j*NT + i]

    __shared__ double u[NT + 1], v[NQ + 1], minv[NQ + 1];
    __shared__ int p[NQ + 1], way[NQ + 1];
    __shared__ unsigned char used[NQ + 1];
    __shared__ int col4row[NT];

    int tid = threadIdx.x;
    const double INF = __builtin_huge_val();

    for (int j = tid; j <= NQ; j += 64) { v[j] = 0.0; p[j] = 0; way[j] = 0; }
    for (int r = tid; r <= NT; r += 64) u[r] = 0.0;
    __syncthreads();

    for (int i = 1; i <= NT; ++i) {
        if (tid == 0) p[0] = i;
        for (int j = tid; j <= NQ; j += 64) { minv[j] = INF; used[j] = 0; }
        __syncthreads();

        int j0 = 0;
        while (true) {
            if (tid == 0) used[j0] = 1;
            __syncthreads();
            int i0 = p[j0];            // uniform
            double ui0 = u[i0];

            // scan columns: update minv/way, compute lane-local argmin over free cols
            double bestv = INF;
            int bestj = NQ + 1;
            for (int j = tid + 1; j <= NQ; j += 64) {
                if (!used[j]) {
                    double mv = minv[j];
                    double cur = (double)Cb[(size_t)(j - 1) * NT + (i0 - 1)] - ui0 - v[j];
                    if (cur < mv) { mv = cur; minv[j] = cur; way[j] = j0; }
                    if (mv < bestv) { bestv = mv; bestj = j; } // strict < keeps smallest j in lane set
                }
            }
            // cross-lane argmin, tie -> smaller column index (matches np.argmin)
            for (int off = 32; off; off >>= 1) {
                double ov = __shfl_down(bestv, off);
                int oj = __shfl_down(bestj, off);
                if (ov < bestv || (ov == bestv && oj < bestj)) { bestv = ov; bestj = oj; }
            }
            double delta = __shfl(bestv, 0);
            int j1 = __shfl(bestj, 0);

            __syncthreads();   // scan reads complete before dual updates
            for (int j = tid; j <= NQ; j += 64) {
                if (used[j]) { u[p[j]] += delta; v[j] -= delta; }  // p[j] distinct across used j
                else         { minv[j] -= delta; }
            }
            j0 = j1;
            __syncthreads();   // updates visible
            if (p[j0] == 0) break;   // uniform
        }
        // augment (serial pointer chase, short path)
        if (tid == 0) {
            int j = j0;
            while (j != 0) { int jn = way[j]; p[j] = p[jn]; j = jn; }
        }
        __syncthreads();
    }

    // col4row[row] = assigned column (query index)
    for (int j = tid + 1; j <= NQ; j += 64) {
        int pj = p[j];
        if (pj > 0) col4row[pj - 1] = j - 1;
    }
    __syncthreads();

    // order = argsort(col4row) (all values distinct): rank by counting
    for (int i = tid; i < NT; i += 64) {
        int ci = col4row[i];
        int rank = 0;
        for (int k = 0; k < NT; ++k) rank += (col4row[k] < ci);
        pred_out[b * NT + rank] = (float)ci;  // sorted query indices
        tgt_out[b * NT + rank] = (float)i;    // corresponding target indices
    }
}

extern "C" void kernel_launch(void* const* d_in, const int* in_sizes, int n_in,
                              void* d_out, int out_size, void* d_ws, size_t ws_size,
                              hipStream_t stream) {
    const float* logits = (const float*)d_in[0];
    const float* boxes  = (const float*)d_in[1];
    const int*   tlab   = (const int*)d_in[2];
    const float* tboxes = (const float*)d_in[3];

    float* out  = (float*)d_out;
    float* C    = out;                                  // 32*900*100
    float* pred = out + (size_t)BS * NQ * NT;           // 32*100
    float* tgt  = pred + BS * NT;                       // 32*100

    cost_kernel<<<BS * NQ, 128, 0, stream>>>(logits, boxes, tlab, tboxes, C);
    jv_kernel<<<BS, 64, 0, stream>>>(C, pred, tgt);
}

// Round 2
// 579.666 us; speedup vs baseline: 1.3073x; 1.3073x over previous
//
#include <hip/hip_runtime.h>
#include <math.h>

#define BS 32
#define NQ 900
#define NC 1203
#define NT 100

// ---------------------------------------------------------------------------
// Kernel 1: cost matrix. One block per (b,q), threads 0..99 cover targets.
// Also writes a transposed copy CT[b][t][q] (into d_ws) so the JV solver can
// read rows of cost.T coalesced. Math kept IDENTICAL to the passing round-1.
// ---------------------------------------------------------------------------
__global__ __launch_bounds__(128) void cost_kernel(
    const float* __restrict__ logits, const float* __restrict__ boxes,
    const int* __restrict__ tlabels, const float* __restrict__ tboxes,
    float* __restrict__ C, float* __restrict__ CT)
{
    int bq = blockIdx.x;
    int b = bq / NQ, q = bq % NQ;
    int t = threadIdx.x;

    const float* pb = boxes + (size_t)(b * NQ + q) * 4;
    float pcx = pb[0], pcy = pb[1], pw = pb[2], ph = pb[3];

    if (t < NT) {
        int id = tlabels[b * NT + t];
        float x = logits[(size_t)(b * NQ + q) * NC + id];
        float prob = 1.0f / (1.0f + expf(-x));
        float neg = 0.75f * (prob * prob) * (-logf(1.0f - prob + 1e-8f));
        float pos = 0.25f * ((1.0f - prob) * (1.0f - prob)) * (-logf(prob + 1e-8f));
        float cclass = pos - neg;

        const float* tb = tboxes + (size_t)(b * NT + t) * 4;
        float tcx = tb[0], tcy = tb[1], tw = tb[2], th = tb[3];
        float cbbox = fabsf(pcx - tcx) + fabsf(pcy - tcy) + fabsf(pw - tw) + fabsf(ph - th);

        float p0 = pcx - 0.5f * pw, p1 = pcy - 0.5f * ph;
        float p2 = pcx + 0.5f * pw, p3 = pcy + 0.5f * ph;
        float t0 = tcx - 0.5f * tw, t1 = tcy - 0.5f * th;
        float t2 = tcx + 0.5f * tw, t3 = tcy + 0.5f * th;
        float area1 = (p2 - p0) * (p3 - p1);
        float area2 = (t2 - t0) * (t3 - t1);
        float ltx = fmaxf(p0, t0), lty = fmaxf(p1, t1);
        float rbx = fminf(p2, t2), rby = fminf(p3, t3);
        float wx = fmaxf(rbx - ltx, 0.0f), wy = fmaxf(rby - lty, 0.0f);
        float inter = wx * wy;
        float uni = area1 + area2 - inter;
        float iou = inter / uni;
        float l2x = fminf(p0, t0), l2y = fminf(p1, t1);
        float r2x = fmaxf(p2, t2), r2y = fmaxf(p3, t3);
        float hx = fmaxf(r2x - l2x, 0.0f), hy = fmaxf(r2y - l2y, 0.0f);
        float hull = hx * hy;
        float giou = iou - (hull - uni) / hull;

        float val = 5.0f * cbbox + 2.0f * cclass + 2.0f * (-giou);
        C[(size_t)(b * NQ + q) * NT + t] = val;
        if (CT) CT[((size_t)b * NT + t) * NQ + q] = val;
    }
}

// ---------------------------------------------------------------------------
// Kernel 2: Jonker-Volgenant LSA on cost.T (n=100 rows, m=900 cols), one wave
// per batch. NEW: row-reduction + greedy-assignment init resolves ~94/100 rows
// without any Dijkstra; remaining free rows use the same shortest-augmenting-
// path loop. Result is the exact LSA optimum (unique w.h.p. for random costs),
// hence identical to the reference's assignment.
// ---------------------------------------------------------------------------
template<bool USE_CT>
__global__ __launch_bounds__(64) void jv_kernel(
    const float* __restrict__ C, const float* __restrict__ CT,
    float* __restrict__ pred_out, float* __restrict__ tgt_out)
{
    int b = blockIdx.x;
    const float* Cb  = C + (size_t)b * NQ * NT;          // C[b][q][t]
    const float* CTb = USE_CT ? CT + (size_t)b * NT * NQ : nullptr;  // CT[b][t][q]

    __shared__ double u[NT + 1], v[NQ + 1], minv[NQ + 1];
    __shared__ int p[NQ + 1], way[NQ + 1];
    __shared__ unsigned char used[NQ + 1];
    __shared__ int col4row[NT];
    __shared__ int amin[NT];
    __shared__ unsigned char done[NT];

    int tid = threadIdx.x;
    const double INF = __builtin_huge_val();

    // cost.T[i][j]: i = target row (0..99), j = query col (0..899)
    auto cost = [&](int i, int j) -> float {
        return USE_CT ? CTb[(size_t)i * NQ + j] : Cb[(size_t)j * NT + i];
    };

    for (int j = tid; j <= NQ; j += 64) { v[j] = 0.0; p[j] = 0; way[j] = 0; }
    __syncthreads();

    // ---- init: per-row min + argmin (coalesced when USE_CT) ----
    for (int i = 0; i < NT; ++i) {
        float bestv = __builtin_huge_valf();
        int bestj = NQ;
        for (int j = tid; j < NQ; j += 64) {
            float c = cost(i, j);
            if (c < bestv) { bestv = c; bestj = j; }
        }
        for (int off = 32; off; off >>= 1) {
            float ov = __shfl_down(bestv, off);
            int oj = __shfl_down(bestj, off);
            if (ov < bestv || (ov == bestv && oj < bestj)) { bestv = ov; bestj = oj; }
        }
        if (tid == 0) { u[i + 1] = (double)bestv; amin[i] = bestj; }
    }
    if (tid == 0) {
        u[0] = 0.0;
        // greedy: assign each row to its argmin column if still free
        for (int i = 1; i <= NT; ++i) {
            int j = amin[i - 1] + 1;
            if (p[j] == 0) { p[j] = i; done[i - 1] = 1; }
            else done[i - 1] = 0;
        }
    }
    __syncthreads();

    // ---- shortest augmenting path for the remaining free rows ----
    for (int i = 1; i <= NT; ++i) {
        if (done[i - 1]) continue;          // uniform (shared, post-sync)
        if (tid == 0) p[0] = i;
        for (int j = tid; j <= NQ; j += 64) { minv[j] = INF; used[j] = 0; }
        __syncthreads();

        int j0 = 0;
        while (true) {
            if (tid == 0) used[j0] = 1;
            __syncthreads();
            int i0 = p[j0];                 // uniform
            double ui0 = u[i0];

            double bestv = INF;
            int bestj = NQ + 1;
            for (int j = tid + 1; j <= NQ; j += 64) {
                if (!used[j]) {
                    double mv = minv[j];
                    double cur = (double)cost(i0 - 1, j - 1) - ui0 - v[j];
                    if (cur < mv) { mv = cur; minv[j] = cur; way[j] = j0; }
                    if (mv < bestv) { bestv = mv; bestj = j; }
                }
            }
            for (int off = 32; off; off >>= 1) {
                double ov = __shfl_down(bestv, off);
                int oj = __shfl_down(bestj, off);
                if (ov < bestv || (ov == bestv && oj < bestj)) { bestv = ov; bestj = oj; }
            }
            double delta = __shfl(bestv, 0);
            int j1 = __shfl(bestj, 0);

            __syncthreads();                // scan reads done before dual updates
            for (int j = tid; j <= NQ; j += 64) {
                if (used[j]) { u[p[j]] += delta; v[j] -= delta; }
                else         { minv[j] -= delta; }
            }
            j0 = j1;
            __syncthreads();
            if (p[j0] == 0) break;          // uniform
        }
        if (tid == 0) {                     // augment
            int j = j0;
            while (j != 0) { int jn = way[j]; p[j] = p[jn]; j = jn; }
        }
        __syncthreads();
    }

    // col4row[row] = assigned column (query index)
    for (int j = tid + 1; j <= NQ; j += 64) {
        int pj = p[j];
        if (pj > 0) col4row[pj - 1] = j - 1;
    }
    __syncthreads();

    // argsort(col4row) via rank-by-counting (values distinct)
    for (int i = tid; i < NT; i += 64) {
        int ci = col4row[i];
        int rank = 0;
        for (int k = 0; k < NT; ++k) rank += (col4row[k] < ci);
        pred_out[b * NT + rank] = (float)ci;
        tgt_out[b * NT + rank] = (float)i;
    }
}

extern "C" void kernel_launch(void* const* d_in, const int* in_sizes, int n_in,
                              void* d_out, int out_size, void* d_ws, size_t ws_size,
                              hipStream_t stream) {
    const float* logits = (const float*)d_in[0];
    const float* boxes  = (const float*)d_in[1];
    const int*   tlab   = (const int*)d_in[2];
    const float* tboxes = (const float*)d_in[3];

    float* out  = (float*)d_out;
    float* C    = out;                                  // 32*900*100
    float* pred = out + (size_t)BS * NQ * NT;           // 32*100
    float* tgt  = pred + BS * NT;                       // 32*100

    const size_t ctBytes = (size_t)BS * NT * NQ * sizeof(float);
    float* CT = (ws_size >= ctBytes) ? (float*)d_ws : nullptr;

    cost_kernel<<<BS * NQ, 128, 0, stream>>>(logits, boxes, tlab, tboxes, C, CT);
    if (CT) jv_kernel<true ><<<BS, 64, 0, stream>>>(C, CT, pred, tgt);
    else    jv_kernel<false><<<BS, 64, 0, stream>>>(C, nullptr, pred, tgt);
}

// Round 3
// 178.863 us; speedup vs baseline: 4.2366x; 3.2408x over previous
//
#include <hip/hip_runtime.h>
#include <math.h>

#define BS 32
#define NQ 900
#define NC 1203
#define NT 100
#define SLOTS 15   // ceil(900/64)

// ---------------------------------------------------------------------------
// Kernel 1: cost matrix (math identical to passing rounds) + transposed CT.
// ---------------------------------------------------------------------------
__global__ __launch_bounds__(128) void cost_kernel(
    const float* __restrict__ logits, const float* __restrict__ boxes,
    const int* __restrict__ tlabels, const float* __restrict__ tboxes,
    float* __restrict__ C, float* __restrict__ CT)
{
    int bq = blockIdx.x;
    int b = bq / NQ, q = bq % NQ;
    int t = threadIdx.x;

    const float* pb = boxes + (size_t)(b * NQ + q) * 4;
    float pcx = pb[0], pcy = pb[1], pw = pb[2], ph = pb[3];

    if (t < NT) {
        int id = tlabels[b * NT + t];
        float x = logits[(size_t)(b * NQ + q) * NC + id];
        float prob = 1.0f / (1.0f + expf(-x));
        float neg = 0.75f * (prob * prob) * (-logf(1.0f - prob + 1e-8f));
        float pos = 0.25f * ((1.0f - prob) * (1.0f - prob)) * (-logf(prob + 1e-8f));
        float cclass = pos - neg;

        const float* tb = tboxes + (size_t)(b * NT + t) * 4;
        float tcx = tb[0], tcy = tb[1], tw = tb[2], th = tb[3];
        float cbbox = fabsf(pcx - tcx) + fabsf(pcy - tcy) + fabsf(pw - tw) + fabsf(ph - th);

        float p0 = pcx - 0.5f * pw, p1 = pcy - 0.5f * ph;
        float p2 = pcx + 0.5f * pw, p3 = pcy + 0.5f * ph;
        float t0 = tcx - 0.5f * tw, t1 = tcy - 0.5f * th;
        float t2 = tcx + 0.5f * tw, t3 = tcy + 0.5f * th;
        float area1 = (p2 - p0) * (p3 - p1);
        float area2 = (t2 - t0) * (t3 - t1);
        float ltx = fmaxf(p0, t0), lty = fmaxf(p1, t1);
        float rbx = fminf(p2, t2), rby = fminf(p3, t3);
        float wx = fmaxf(rbx - ltx, 0.0f), wy = fmaxf(rby - lty, 0.0f);
        float inter = wx * wy;
        float uni = area1 + area2 - inter;
        float iou = inter / uni;
        float l2x = fminf(p0, t0), l2y = fminf(p1, t1);
        float r2x = fmaxf(p2, t2), r2y = fmaxf(p3, t3);
        float hx = fmaxf(r2x - l2x, 0.0f), hy = fmaxf(r2y - l2y, 0.0f);
        float hull = hx * hy;
        float giou = iou - (hull - uni) / hull;

        float val = 5.0f * cbbox + 2.0f * cclass + 2.0f * (-giou);
        C[(size_t)(b * NQ + q) * NT + t] = val;
        if (CT) CT[((size_t)b * NT + t) * NQ + q] = val;
    }
}

// ---------------------------------------------------------------------------
// Kernel 2: per-row min+argmin of cost.T, fully parallel (one block per row).
// Results stashed in the pred/tgt output region (overwritten later by jv).
// ---------------------------------------------------------------------------
__global__ __launch_bounds__(64) void rowmin_kernel(
    const float* __restrict__ CT, float* __restrict__ u0, int* __restrict__ amin)
{
    int bi = blockIdx.x;                    // b*NT + i
    const float* row = CT + (size_t)bi * NQ;
    int tid = threadIdx.x;
    float bestv = __builtin_huge_valf();
    int bestj = NQ;
    for (int j = tid; j < NQ; j += 64) {
        float c = row[j];
        if (c < bestv) { bestv = c; bestj = j; }
    }
    for (int off = 32; off; off >>= 1) {
        float ov = __shfl_down(bestv, off);
        int  oj = __shfl_down(bestj, off);
        if (ov < bestv || (ov == bestv && oj < bestj)) { bestv = ov; bestj = oj; }
    }
    if (tid == 0) { u0[bi] = bestv; amin[bi] = bestj; }
}

// ---------------------------------------------------------------------------
// Kernel 3: JV solver, one wave per batch.
// greedy (parallel claim) -> ARR -> deferred-dual Dijkstra (scipy-style).
// Exact LSA optimum == reference (unique optimum for continuous random costs).
// ---------------------------------------------------------------------------
template<bool USE_CT>
__global__ __launch_bounds__(64) void jv_kernel(
    const float* __restrict__ C, const float* __restrict__ CT,
    const float* __restrict__ u0g, const int* __restrict__ aming,
    float* __restrict__ pred_out, float* __restrict__ tgt_out)
{
    int b = blockIdx.x;
    const float* Cb  = C + (size_t)b * NQ * NT;
    const float* CTb = USE_CT ? CT + (size_t)b * NT * NQ : nullptr;
    int tid = threadIdx.x;
    const double INF = __builtin_huge_val();

    __shared__ double u[NT];
    __shared__ double vsh[NQ];
    __shared__ double spsh[NQ];
    __shared__ int path[NQ];
    __shared__ int row4col[NQ];
    __shared__ int col4row[NT];
    __shared__ int aminsh[NT];
    __shared__ int freeRows[NT + 4];
    __shared__ int srList[136];
    __shared__ int nFreeSh;

    auto cost = [&](int i, int j) -> float {
        return USE_CT ? CTb[(size_t)i * NQ + j] : Cb[(size_t)j * NT + i];
    };

    // ---- phase A: init state ----
    for (int j = tid; j < NQ; j += 64) { vsh[j] = 0.0; row4col[j] = 0x7fffffff; }
    for (int i = tid; i < NT; i += 64) col4row[i] = -1;
    if (tid == 0) nFreeSh = 0;

    if (u0g) {
        for (int i = tid; i < NT; i += 64) {
            u[i] = (double)u0g[b * NT + i];
            aminsh[i] = aming[b * NT + i];
        }
        __syncthreads();
    } else {
        __syncthreads();
        // fallback: internal row-min scans
        for (int i = 0; i < NT; ++i) {
            float bestv = __builtin_huge_valf(); int bestj = 0;
            for (int j = tid; j < NQ; j += 64) {
                float c = cost(i, j);
                if (c < bestv) { bestv = c; bestj = j; }
            }
            for (int off = 32; off; off >>= 1) {
                float ov = __shfl_down(bestv, off);
                int  oj = __shfl_down(bestj, off);
                if (ov < bestv || (ov == bestv && oj < bestj)) { bestv = ov; bestj = oj; }
            }
            if (tid == 0) { u[i] = (double)bestv; aminsh[i] = bestj; }
        }
        __syncthreads();
    }

    // ---- phase B: greedy claim (parallel) ----
    for (int i = tid; i < NT; i += 64) atomicMin(&row4col[aminsh[i]], i);
    __syncthreads();
    for (int i = tid; i < NT; i += 64) {
        int j = aminsh[i];
        if (row4col[j] == i) col4row[i] = j;
        else { int pos = atomicAdd(&nFreeSh, 1); freeRows[pos] = i; }
    }
    __syncthreads();
    for (int j = tid; j < NQ; j += 64)
        if (row4col[j] == 0x7fffffff) row4col[j] = -1;
    __syncthreads();

    // ---- phase C: augmenting row reduction (LAPJV-style) ----
    int steps = 0;
    while (true) {
        __syncthreads();
        int nf = nFreeSh;
        if (nf == 0 || steps >= 512) break;
        int i = freeRows[nf - 1];
        const float* rowp = USE_CT ? (CTb + (size_t)i * NQ) : nullptr;

        double m1 = INF, m2 = INF; int j1 = 0;
        for (int j = tid; j < NQ; j += 64) {
            float c = USE_CT ? rowp[j] : Cb[(size_t)j * NT + i];
            double cur = (double)c - vsh[j];
            if (cur < m1) { m2 = m1; m1 = cur; j1 = j; }
            else if (cur < m2) m2 = cur;
        }
        for (int off = 32; off; off >>= 1) {
            double o1 = __shfl_down(m1, off); int oj = __shfl_down(j1, off);
            double o2 = __shfl_down(m2, off);
            if (o1 < m1 || (o1 == m1 && oj < j1)) { m2 = fmin(m1, o2); m1 = o1; j1 = oj; }
            else m2 = fmin(m2, o1);
        }
        if (tid == 0) {
            u[i] = m2;
            if (m1 < m2) vsh[j1] -= (m2 - m1);
            int k = row4col[j1];
            row4col[j1] = i; col4row[i] = j1;
            int nf2 = nf - 1;
            if (k >= 0) { col4row[k] = -1; freeRows[nf2++] = k; }
            nFreeSh = nf2;
        }
        steps++;
    }
    __syncthreads();

    // ---- phase D: deferred-dual Dijkstra for remaining free rows ----
    int nf = nFreeSh;
    for (int f = 0; f < nf; ++f) {
        int curRow = freeRows[f];
        double minv[SLOTS];
        #pragma unroll
        for (int k = 0; k < SLOTS; ++k) minv[k] = INF;
        unsigned scMask = 0;
        double minVal = 0.0;
        int i = curRow, nIter = 0, sink = -1;

        while (sink < 0) {
            if (tid == 0) srList[nIter] = i;
            double ui = u[i];
            const float* rowp = USE_CT ? (CTb + (size_t)i * NQ) : nullptr;
            double lbest = INF; int lbestj = 0x7fffffff;
            #pragma unroll
            for (int k = 0; k < SLOTS; ++k) {
                int j = (k << 6) + tid;
                bool ok = (k < SLOTS - 1) || (j < NQ);
                if (ok && !((scMask >> k) & 1u)) {
                    float c = USE_CT ? rowp[j] : Cb[(size_t)j * NT + i];
                    double cur = minVal + (double)c - ui - vsh[j];
                    if (cur < minv[k]) { minv[k] = cur; spsh[j] = cur; path[j] = i; }
                    double mk = minv[k];
                    if (mk < lbest || (mk == lbest && j < lbestj)) { lbest = mk; lbestj = j; }
                }
            }
            for (int off = 32; off; off >>= 1) {
                double ov = __shfl_down(lbest, off);
                int  oj = __shfl_down(lbestj, off);
                if (ov < lbest || (ov == lbest && oj < lbestj)) { lbest = ov; lbestj = oj; }
            }
            minVal = __shfl(lbest, 0);
            int j1 = __shfl(lbestj, 0);
            if (tid == (j1 & 63)) scMask |= (1u << (j1 >> 6));
            int r = row4col[j1];
            nIter++;
            if (r < 0 || nIter >= 127) sink = j1;
            else i = r;
        }
        __syncthreads();   // spsh/path visible to tid0; scan reads done

        if (tid == 0) {
            u[curRow] += minVal;
            for (int t2 = 1; t2 < nIter; ++t2) {
                int ri = srList[t2];
                u[ri] += minVal - spsh[col4row[ri]];
            }
        }
        #pragma unroll
        for (int k = 0; k < SLOTS; ++k) {
            int j = (k << 6) + tid;
            bool ok = (k < SLOTS - 1) || (j < NQ);
            if (ok && ((scMask >> k) & 1u)) vsh[j] -= minVal - minv[k];
        }
        if (tid == 0) {
            int j = sink, guard = 0;
            while (guard++ < 128) {
                int ri = path[j];
                row4col[j] = ri;
                int t2 = col4row[ri]; col4row[ri] = j;
                j = t2;
                if (ri == curRow) break;
            }
        }
        __syncthreads();
    }

    // ---- epilogue: rank-sort col4row, write indices ----
    __syncthreads();
    for (int i2 = tid; i2 < NT; i2 += 64) {
        int ci = col4row[i2];
        int rank = 0;
        for (int k2 = 0; k2 < NT; ++k2) rank += (col4row[k2] < ci);
        pred_out[b * NT + rank] = (float)ci;
        tgt_out[b * NT + rank] = (float)i2;
    }
}

extern "C" void kernel_launch(void* const* d_in, const int* in_sizes, int n_in,
                              void* d_out, int out_size, void* d_ws, size_t ws_size,
                              hipStream_t stream) {
    const float* logits = (const float*)d_in[0];
    const float* boxes  = (const float*)d_in[1];
    const int*   tlab   = (const int*)d_in[2];
    const float* tboxes = (const float*)d_in[3];

    float* out  = (float*)d_out;
    float* C    = out;                                  // 32*900*100
    float* pred = out + (size_t)BS * NQ * NT;           // 32*100
    float* tgt  = pred + BS * NT;                       // 32*100

    const size_t ctBytes = (size_t)BS * NT * NQ * sizeof(float);
    float* CT = (ws_size >= ctBytes) ? (float*)d_ws : nullptr;

    cost_kernel<<<BS * NQ, 128, 0, stream>>>(logits, boxes, tlab, tboxes, C, CT);

    if (CT) {
        // stash row-min results in the pred/tgt region; jv reads then overwrites
        float* u0 = pred;          // 3200 floats
        int* amin = (int*)tgt;     // 3200 ints
        rowmin_kernel<<<BS * NT, 64, 0, stream>>>(CT, u0, amin);
        jv_kernel<true ><<<BS, 64, 0, stream>>>(C, CT, u0, amin, pred, tgt);
    } else {
        jv_kernel<false><<<BS, 64, 0, stream>>>(C, nullptr, nullptr, nullptr, pred, tgt);
    }
}

// Round 4
// 169.580 us; speedup vs baseline: 4.4685x; 1.0547x over previous
//
#include <hip/hip_runtime.h>
#include <math.h>

#define BS 32
#define NQ 900
#define NC 1203
#define NT 100
#define SLOTS 15   // ceil(900/64)
#define BLK 256
#define NWAVES 4

// ---------------------------------------------------------------------------
// Kernel 1: cost matrix (math identical to passing rounds) + optional CT.
// ---------------------------------------------------------------------------
__global__ __launch_bounds__(128) void cost_kernel(
    const float* __restrict__ logits, const float* __restrict__ boxes,
    const int* __restrict__ tlabels, const float* __restrict__ tboxes,
    float* __restrict__ C, float* __restrict__ CT)
{
    int bq = blockIdx.x;
    int b = bq / NQ, q = bq % NQ;
    int t = threadIdx.x;

    const float* pb = boxes + (size_t)(b * NQ + q) * 4;
    float pcx = pb[0], pcy = pb[1], pw = pb[2], ph = pb[3];

    if (t < NT) {
        int id = tlabels[b * NT + t];
        float x = logits[(size_t)(b * NQ + q) * NC + id];
        float prob = 1.0f / (1.0f + expf(-x));
        float neg = 0.75f * (prob * prob) * (-logf(1.0f - prob + 1e-8f));
        float pos = 0.25f * ((1.0f - prob) * (1.0f - prob)) * (-logf(prob + 1e-8f));
        float cclass = pos - neg;

        const float* tb = tboxes + (size_t)(b * NT + t) * 4;
        float tcx = tb[0], tcy = tb[1], tw = tb[2], th = tb[3];
        float cbbox = fabsf(pcx - tcx) + fabsf(pcy - tcy) + fabsf(pw - tw) + fabsf(ph - th);

        float p0 = pcx - 0.5f * pw, p1 = pcy - 0.5f * ph;
        float p2 = pcx + 0.5f * pw, p3 = pcy + 0.5f * ph;
        float t0 = tcx - 0.5f * tw, t1 = tcy - 0.5f * th;
        float t2 = tcx + 0.5f * tw, t3 = tcy + 0.5f * th;
        float area1 = (p2 - p0) * (p3 - p1);
        float area2 = (t2 - t0) * (t3 - t1);
        float ltx = fmaxf(p0, t0), lty = fmaxf(p1, t1);
        float rbx = fminf(p2, t2), rby = fminf(p3, t3);
        float wx = fmaxf(rbx - ltx, 0.0f), wy = fmaxf(rby - lty, 0.0f);
        float inter = wx * wy;
        float uni = area1 + area2 - inter;
        float iou = inter / uni;
        float l2x = fminf(p0, t0), l2y = fminf(p1, t1);
        float r2x = fmaxf(p2, t2), r2y = fmaxf(p3, t3);
        float hx = fmaxf(r2x - l2x, 0.0f), hy = fmaxf(r2y - l2y, 0.0f);
        float hull = hx * hy;
        float giou = iou - (hull - uni) / hull;

        float val = 5.0f * cbbox + 2.0f * cclass + 2.0f * (-giou);
        C[(size_t)(b * NQ + q) * NT + t] = val;
        if (CT) CT[((size_t)b * NT + t) * NQ + q] = val;
    }
}

// ---------------------------------------------------------------------------
// Kernel 2: JV solver, one block (4 waves) per batch.
// A: parallel row-min (coalesced from C, no CT needed)
// B: greedy claim  C: 4-way batched ARR (stale-commit with collision refusal)
// D: deferred-dual Dijkstra backstop (redundant across waves, guarded writes)
// ---------------------------------------------------------------------------
template<bool USE_CT>
__global__ __launch_bounds__(BLK) void jv_kernel(
    const float* __restrict__ C, const float* __restrict__ CT,
    float* __restrict__ pred_out, float* __restrict__ tgt_out)
{
    int b = blockIdx.x;
    const float* Cb  = C + (size_t)b * NQ * NT;
    const float* CTb = USE_CT ? CT + (size_t)b * NT * NQ : nullptr;
    int tid = threadIdx.x;
    int w = tid >> 6, lane = tid & 63;
    const double INF = __builtin_huge_val();

    __shared__ double u[NT];
    __shared__ double vsh[NQ];
    __shared__ double spsh[NQ];
    __shared__ int path[NQ];
    __shared__ int row4col[NQ];
    __shared__ int col4row[NT];
    __shared__ int aminsh[NT];
    __shared__ int freeRows[NT + 8];
    __shared__ int srList[136];
    __shared__ float pm[2][NT];
    __shared__ int pq[2][NT];
    __shared__ double pm1[NWAVES], pm2[NWAVES];
    __shared__ int pj1[NWAVES], prow[NWAVES];
    __shared__ int nFreeSh;

    // ---- phase A: init + parallel row-min (threads own targets; coalesced) ----
    for (int j = tid; j < NQ; j += BLK) { vsh[j] = 0.0; row4col[j] = 0x7fffffff; }
    {
        int half = -1, t = -1;
        if (tid < NT) { half = 0; t = tid; }
        else if (tid >= 128 && tid < 128 + NT) { half = 1; t = tid - 128; }
        if (half >= 0) {
            int q0 = half * 450, q1 = q0 + 450;
            float best = __builtin_huge_valf(); int bq = q0;
            #pragma unroll 4
            for (int q = q0; q < q1; ++q) {
                float c = Cb[(size_t)q * NT + t];
                if (c < best) { best = c; bq = q; }
            }
            pm[half][t] = best; pq[half][t] = bq;
        }
        __syncthreads();
        if (tid < NT) {
            float v0 = pm[0][tid], v1 = pm[1][tid];
            float bv = (v1 < v0) ? v1 : v0;          // tie -> smaller q (half 0)
            int bj = (v1 < v0) ? pq[1][tid] : pq[0][tid];
            u[tid] = (double)bv; aminsh[tid] = bj;
        }
    }
    __syncthreads();

    // ---- phase B: greedy claim (smallest row wins a contested column) ----
    for (int i = tid; i < NT; i += BLK) atomicMin(&row4col[aminsh[i]], i);
    __syncthreads();
    if (tid == 0) {
        int n = 0;
        for (int i = 0; i < NT; ++i) {
            int j = aminsh[i];
            if (row4col[j] == i) col4row[i] = j;
            else { col4row[i] = -1; freeRows[n++] = i; }
        }
        nFreeSh = n;
    }
    __syncthreads();
    for (int j = tid; j < NQ; j += BLK)
        if (row4col[j] == 0x7fffffff) row4col[j] = -1;

    // ---- phase C: 4-way batched augmenting row reduction ----
    int guard = 0;
    while (guard++ < 400) {
        __syncthreads();
        int nf = nFreeSh;
        if (nf == 0) break;
        int take = nf < NWAVES ? nf : NWAVES;
        if (w < take) {
            int i = freeRows[nf - 1 - w];
            double m1 = INF, m2 = INF; int j1 = 0;
            for (int j = lane; j < NQ; j += 64) {
                float c = USE_CT ? CTb[(size_t)i * NQ + j] : Cb[(size_t)j * NT + i];
                double cur = (double)c - vsh[j];
                if (cur < m1) { m2 = m1; m1 = cur; j1 = j; }
                else if (cur < m2) m2 = cur;
            }
            for (int off = 32; off; off >>= 1) {
                double o1 = __shfl_down(m1, off); int oj = __shfl_down(j1, off);
                double o2 = __shfl_down(m2, off);
                if (o1 < m1 || (o1 == m1 && oj < j1)) { m2 = fmin(m1, o2); m1 = o1; j1 = oj; }
                else m2 = fmin(m2, o1);
            }
            if (lane == 0) { pm1[w] = m1; pm2[w] = m2; pj1[w] = j1; prow[w] = i; }
        }
        __syncthreads();
        if (tid == 0) {
            int n = nf - take;
            int cj[NWAVES]; int nc = 0;
            for (int k = 0; k < take; ++k) {
                int j1 = pj1[k], i = prow[k];
                bool clash = false;
                for (int k2 = 0; k2 < nc; ++k2) if (cj[k2] == j1) clash = true;
                if (clash) { freeRows[n++] = i; continue; }
                cj[nc++] = j1;
                double m1 = pm1[k], m2 = pm2[k];
                u[i] = m2;
                vsh[j1] -= (m2 - m1);
                int inc = row4col[j1];
                row4col[j1] = i; col4row[i] = j1;
                if (inc >= 0) { col4row[inc] = -1; freeRows[n++] = inc; }
            }
            nFreeSh = n;
        }
    }
    __syncthreads();

    // ---- phase D: deferred-dual Dijkstra backstop (redundant across waves) ----
    int nf2 = nFreeSh;
    for (int f = 0; f < nf2; ++f) {
        int curRow = freeRows[f];
        double minv[SLOTS];
        #pragma unroll
        for (int k = 0; k < SLOTS; ++k) minv[k] = INF;
        unsigned scMask = 0;
        double minVal = 0.0;
        int i = curRow, nIter = 0, sink = -1;

        while (sink < 0) {
            if (tid == 0) srList[nIter] = i;
            double ui = u[i];
            double lbest = INF; int lbestj = 0x7fffffff;
            #pragma unroll
            for (int k = 0; k < SLOTS; ++k) {
                int j = (k << 6) + lane;
                bool ok = (k < SLOTS - 1) || (j < NQ);
                if (ok && !((scMask >> k) & 1u)) {
                    float c = USE_CT ? CTb[(size_t)i * NQ + j] : Cb[(size_t)j * NT + i];
                    double cur = minVal + (double)c - ui - vsh[j];
                    if (cur < minv[k]) { minv[k] = cur; spsh[j] = cur; path[j] = i; }
                    double mk = minv[k];
                    if (mk < lbest || (mk == lbest && j < lbestj)) { lbest = mk; lbestj = j; }
                }
            }
            for (int off = 32; off; off >>= 1) {
                double ov = __shfl_down(lbest, off);
                int  oj = __shfl_down(lbestj, off);
                if (ov < lbest || (ov == lbest && oj < lbestj)) { lbest = ov; lbestj = oj; }
            }
            minVal = __shfl(lbest, 0);
            int j1 = __shfl(lbestj, 0);
            if (lane == (j1 & 63)) scMask |= (1u << (j1 >> 6));
            int r = row4col[j1];
            nIter++;
            if (r < 0 || nIter >= 127) sink = j1;
            else i = r;
        }
        __syncthreads();   // all redundant waves done; spsh/path stable

        if (tid == 0) {
            u[curRow] += minVal;
            for (int t2 = 1; t2 < nIter; ++t2) {
                int ri = srList[t2];
                u[ri] += minVal - spsh[col4row[ri]];
            }
        }
        if (tid < 64) {    // only wave 0 applies the v update
            #pragma unroll
            for (int k = 0; k < SLOTS; ++k) {
                int j = (k << 6) + lane;
                bool ok = (k < SLOTS - 1) || (j < NQ);
                if (ok && ((scMask >> k) & 1u)) vsh[j] -= minVal - minv[k];
            }
        }
        if (tid == 0) {    // augment
            int j = sink, g2 = 0;
            while (g2++ < 128) {
                int ri = path[j];
                row4col[j] = ri;
                int t2 = col4row[ri]; col4row[ri] = j;
                j = t2;
                if (ri == curRow) break;
            }
        }
        __syncthreads();
    }

    // ---- epilogue: rank-sort col4row, write indices ----
    __syncthreads();
    for (int i2 = tid; i2 < NT; i2 += BLK) {
        int ci = col4row[i2];
        int rank = 0;
        for (int k2 = 0; k2 < NT; ++k2) rank += (col4row[k2] < ci);
        pred_out[b * NT + rank] = (float)ci;
        tgt_out[b * NT + rank] = (float)i2;
    }
}

extern "C" void kernel_launch(void* const* d_in, const int* in_sizes, int n_in,
                              void* d_out, int out_size, void* d_ws, size_t ws_size,
                              hipStream_t stream) {
    const float* logits = (const float*)d_in[0];
    const float* boxes  = (const float*)d_in[1];
    const int*   tlab   = (const int*)d_in[2];
    const float* tboxes = (const float*)d_in[3];

    float* out  = (float*)d_out;
    float* C    = out;                                  // 32*900*100
    float* pred = out + (size_t)BS * NQ * NT;           // 32*100
    float* tgt  = pred + BS * NT;                       // 32*100

    const size_t ctBytes = (size_t)BS * NT * NQ * sizeof(float);
    float* CT = (ws_size >= ctBytes) ? (float*)d_ws : nullptr;

    cost_kernel<<<BS * NQ, 128, 0, stream>>>(logits, boxes, tlab, tboxes, C, CT);
    if (CT) jv_kernel<true ><<<BS, BLK, 0, stream>>>(C, CT, pred, tgt);
    else    jv_kernel<false><<<BS, BLK, 0, stream>>>(C, nullptr, pred, tgt);
}

// Round 5
// 163.256 us; speedup vs baseline: 4.6416x; 1.0387x over previous
//
#include <hip/hip_runtime.h>
#include <math.h>

#define BS 32
#define NQ 900
#define NC 1203
#define NT 100
#define SLOTS 15   // ceil(900/64)

// ---------------------------------------------------------------------------
// Kernel 1: cost matrix (math identical to passing rounds) + transposed CT.
// ---------------------------------------------------------------------------
__global__ __launch_bounds__(128) void cost_kernel(
    const float* __restrict__ logits, const float* __restrict__ boxes,
    const int* __restrict__ tlabels, const float* __restrict__ tboxes,
    float* __restrict__ C, float* __restrict__ CT)
{
    int bq = blockIdx.x;
    int b = bq / NQ, q = bq % NQ;
    int t = threadIdx.x;

    const float* pb = boxes + (size_t)(b * NQ + q) * 4;
    float pcx = pb[0], pcy = pb[1], pw = pb[2], ph = pb[3];

    if (t < NT) {
        int id = tlabels[b * NT + t];
        float x = logits[(size_t)(b * NQ + q) * NC + id];
        float prob = 1.0f / (1.0f + expf(-x));
        float neg = 0.75f * (prob * prob) * (-logf(1.0f - prob + 1e-8f));
        float pos = 0.25f * ((1.0f - prob) * (1.0f - prob)) * (-logf(prob + 1e-8f));
        float cclass = pos - neg;

        const float* tb = tboxes + (size_t)(b * NT + t) * 4;
        float tcx = tb[0], tcy = tb[1], tw = tb[2], th = tb[3];
        float cbbox = fabsf(pcx - tcx) + fabsf(pcy - tcy) + fabsf(pw - tw) + fabsf(ph - th);

        float p0 = pcx - 0.5f * pw, p1 = pcy - 0.5f * ph;
        float p2 = pcx + 0.5f * pw, p3 = pcy + 0.5f * ph;
        float t0 = tcx - 0.5f * tw, t1 = tcy - 0.5f * th;
        float t2 = tcx + 0.5f * tw, t3 = tcy + 0.5f * th;
        float area1 = (p2 - p0) * (p3 - p1);
        float area2 = (t2 - t0) * (t3 - t1);
        float ltx = fmaxf(p0, t0), lty = fmaxf(p1, t1);
        float rbx = fminf(p2, t2), rby = fminf(p3, t3);
        float wx = fmaxf(rbx - ltx, 0.0f), wy = fmaxf(rby - lty, 0.0f);
        float inter = wx * wy;
        float uni = area1 + area2 - inter;
        float iou = inter / uni;
        float l2x = fminf(p0, t0), l2y = fminf(p1, t1);
        float r2x = fmaxf(p2, t2), r2y = fmaxf(p3, t3);
        float hx = fmaxf(r2x - l2x, 0.0f), hy = fmaxf(r2y - l2y, 0.0f);
        float hull = hx * hy;
        float giou = iou - (hull - uni) / hull;

        float val = 5.0f * cbbox + 2.0f * cclass + 2.0f * (-giou);
        C[(size_t)(b * NQ + q) * NT + t] = val;
        if (CT) CT[((size_t)b * NT + t) * NQ + q] = val;
    }
}

// ---------------------------------------------------------------------------
// Kernel 2: per-row min+argmin of cost.T, fully parallel (one block per row).
// Results stashed in the pred/tgt output region (overwritten later by jv).
// ---------------------------------------------------------------------------
__global__ __launch_bounds__(64) void rowmin_kernel(
    const float* __restrict__ CT, float* __restrict__ u0, int* __restrict__ amin)
{
    int bi = blockIdx.x;                    // b*NT + i
    const float* row = CT + (size_t)bi * NQ;
    int tid = threadIdx.x;
    float bestv = __builtin_huge_valf();
    int bestj = NQ;
    #pragma unroll
    for (int k = 0; k < SLOTS; ++k) {
        int j = (k << 6) + tid;
        if ((k < SLOTS - 1) || (j < NQ)) {
            float c = row[j];
            if (c < bestv) { bestv = c; bestj = j; }
        }
    }
    for (int off = 32; off; off >>= 1) {
        float ov = __shfl_down(bestv, off);
        int  oj = __shfl_down(bestj, off);
        if (ov < bestv || (ov == bestv && oj < bestj)) { bestv = ov; bestj = oj; }
    }
    if (tid == 0) { u0[bi] = bestv; amin[bi] = bestj; }
}

// ---------------------------------------------------------------------------
// Kernel 3: JV solver, ONE WAVE (64 threads) per batch.
// A: load stashed row mins   B: greedy claim
// C: ARR with 2-visit cap (LAPJV discipline -- kills ping-pong)
// D: deferred-dual Dijkstra (scipy rectangular_lsap) for parked rows
// Exact LSA optimum == reference (optimum unique for continuous random costs).
// ---------------------------------------------------------------------------
template<bool USE_CT>
__global__ __launch_bounds__(64) void jv_kernel(
    const float* __restrict__ C, const float* __restrict__ CT,
    const float* __restrict__ u0g, const int* __restrict__ aming,
    float* __restrict__ pred_out, float* __restrict__ tgt_out)
{
    int b = blockIdx.x;
    const float* Cb  = C + (size_t)b * NQ * NT;
    const float* CTb = USE_CT ? CT + (size_t)b * NT * NQ : nullptr;
    int lane = threadIdx.x;
    const double INF = __builtin_huge_val();

    __shared__ double u[NT];
    __shared__ double vsh[NQ];
    __shared__ double spsh[NQ];
    __shared__ int path[NQ];
    __shared__ int row4col[NQ];
    __shared__ int col4row[NT];
    __shared__ int aminsh[NT];
    __shared__ int freeRows[NT + 4];
    __shared__ int parked[NT];
    __shared__ int srList[136];
    __shared__ unsigned char visits[NT];
    __shared__ int nFreeSh, nParkSh;

    // ---- phase A: init ----
    for (int j = lane; j < NQ; j += 64) { vsh[j] = 0.0; row4col[j] = 0x7fffffff; }
    for (int i = lane; i < NT; i += 64) visits[i] = 0;
    if (lane == 0) { nFreeSh = 0; nParkSh = 0; }

    if (USE_CT && u0g) {
        for (int i = lane; i < NT; i += 64) {
            u[i] = (double)u0g[b * NT + i];
            aminsh[i] = aming[b * NT + i];
        }
        __syncthreads();
    } else {
        __syncthreads();
        for (int i = 0; i < NT; ++i) {              // fallback: serial row mins
            float bestv = __builtin_huge_valf(); int bestj = 0;
            for (int j = lane; j < NQ; j += 64) {
                float c = Cb[(size_t)j * NT + i];
                if (c < bestv) { bestv = c; bestj = j; }
            }
            for (int off = 32; off; off >>= 1) {
                float ov = __shfl_down(bestv, off);
                int  oj = __shfl_down(bestj, off);
                if (ov < bestv || (ov == bestv && oj < bestj)) { bestv = ov; bestj = oj; }
            }
            if (lane == 0) { u[i] = (double)bestv; aminsh[i] = bestj; }
        }
        __syncthreads();
    }

    // ---- phase B: greedy claim (smallest row wins a contested column) ----
    for (int i = lane; i < NT; i += 64) atomicMin(&row4col[aminsh[i]], i);
    __syncthreads();
    if (lane == 0) {
        int n = 0;
        for (int i = 0; i < NT; ++i) {
            int j = aminsh[i];
            if (row4col[j] == i) col4row[i] = j;
            else { col4row[i] = -1; freeRows[n++] = i; }
        }
        nFreeSh = n;
    }
    __syncthreads();
    for (int j = lane; j < NQ; j += 64)
        if (row4col[j] == 0x7fffffff) row4col[j] = -1;
    __syncthreads();

    // ---- phase C: ARR with 2-visit cap ----
    int guard = 0;
    while (guard++ < 300) {
        int nf = nFreeSh;                          // uniform
        if (nf == 0) break;
        int i = freeRows[nf - 1];                  // uniform
        if (visits[i] >= 2) {                      // park for Dijkstra
            if (lane == 0) { nFreeSh = nf - 1; parked[nParkSh] = i; nParkSh++; }
            __syncthreads();
            continue;
        }
        if (lane == 0) visits[i]++;

        const float* rowp = USE_CT ? (CTb + (size_t)i * NQ) : nullptr;
        double m1 = INF, m2 = INF; int j1 = 0;
        #pragma unroll
        for (int k = 0; k < SLOTS; ++k) {
            int j = (k << 6) + lane;
            if ((k < SLOTS - 1) || (j < NQ)) {
                float c = USE_CT ? rowp[j] : Cb[(size_t)j * NT + i];
                double cur = (double)c - vsh[j];
                if (cur < m1) { m2 = m1; m1 = cur; j1 = j; }
                else if (cur < m2) m2 = cur;
            }
        }
        for (int off = 32; off; off >>= 1) {
            double o1 = __shfl_down(m1, off); int oj = __shfl_down(j1, off);
            double o2 = __shfl_down(m2, off);
            if (o1 < m1 || (o1 == m1 && oj < j1)) { m2 = fmin(m1, o2); m1 = o1; j1 = oj; }
            else m2 = fmin(m2, o1);
        }
        if (lane == 0) {
            u[i] = m2;
            vsh[j1] -= (m2 - m1);
            int inc = row4col[j1];
            row4col[j1] = i; col4row[i] = j1;
            int n = nf - 1;
            if (inc >= 0) { col4row[inc] = -1; freeRows[n++] = inc; }
            nFreeSh = n;
        }
        __syncthreads();
    }
    // spill anything left to parked
    if (lane == 0) {
        while (nFreeSh > 0) { nFreeSh--; parked[nParkSh] = freeRows[nFreeSh]; nParkSh++; }
    }
    __syncthreads();

    // ---- phase D: deferred-dual Dijkstra (scipy-style) for parked rows ----
    int np = nParkSh;
    for (int f = 0; f < np; ++f) {
        int curRow = parked[f];
        double minv[SLOTS];
        #pragma unroll
        for (int k = 0; k < SLOTS; ++k) minv[k] = INF;
        unsigned scMask = 0;
        double minVal = 0.0;
        int i = curRow, nIter = 0, sink = -1;

        while (sink < 0) {
            if (lane == 0) srList[nIter] = i;
            double ui = u[i];
            const float* rowp = USE_CT ? (CTb + (size_t)i * NQ) : nullptr;
            double lbest = INF; int lbestj = 0x7fffffff;
            #pragma unroll
            for (int k = 0; k < SLOTS; ++k) {
                int j = (k << 6) + lane;
                bool ok = (k < SLOTS - 1) || (j < NQ);
                if (ok && !((scMask >> k) & 1u)) {
                    float c = USE_CT ? rowp[j] : Cb[(size_t)j * NT + i];
                    double cur = minVal + (double)c - ui - vsh[j];
                    if (cur < minv[k]) { minv[k] = cur; spsh[j] = cur; path[j] = i; }
                    double mk = minv[k];
                    if (mk < lbest || (mk == lbest && j < lbestj)) { lbest = mk; lbestj = j; }
                }
            }
            for (int off = 32; off; off >>= 1) {
                double ov = __shfl_down(lbest, off);
                int  oj = __shfl_down(lbestj, off);
                if (ov < lbest || (ov == lbest && oj < lbestj)) { lbest = ov; lbestj = oj; }
            }
            minVal = __shfl(lbest, 0);
            int j1 = __shfl(lbestj, 0);
            if (lane == (j1 & 63)) scMask |= (1u << (j1 >> 6));
            int r = row4col[j1];
            nIter++;
            if (r < 0 || nIter >= 127) sink = j1;
            else i = r;
        }
        __syncthreads();   // spsh/path stable before dual updates

        if (lane == 0) {
            u[curRow] += minVal;
            for (int t2 = 1; t2 < nIter; ++t2) {
                int ri = srList[t2];
                u[ri] += minVal - spsh[col4row[ri]];   // pre-augment col4row
            }
        }
        #pragma unroll
        for (int k = 0; k < SLOTS; ++k) {
            int j = (k << 6) + lane;
            bool ok = (k < SLOTS - 1) || (j < NQ);
            if (ok && ((scMask >> k) & 1u)) vsh[j] -= minVal - minv[k];
        }
        if (lane == 0) {   // augment
            int j = sink, g2 = 0;
            while (g2++ < 128) {
                int ri = path[j];
                row4col[j] = ri;
                int t2 = col4row[ri]; col4row[ri] = j;
                j = t2;
                if (ri == curRow) break;
            }
        }
        __syncthreads();
    }

    // ---- epilogue: rank-sort col4row, write indices ----
    for (int i2 = lane; i2 < NT; i2 += 64) {
        int ci = col4row[i2];
        int rank = 0;
        for (int k2 = 0; k2 < NT; ++k2) rank += (col4row[k2] < ci);
        pred_out[b * NT + rank] = (float)ci;
        tgt_out[b * NT + rank] = (float)i2;
    }
}

extern "C" void kernel_launch(void* const* d_in, const int* in_sizes, int n_in,
                              void* d_out, int out_size, void* d_ws, size_t ws_size,
                              hipStream_t stream) {
    const float* logits = (const float*)d_in[0];
    const float* boxes  = (const float*)d_in[1];
    const int*   tlab   = (const int*)d_in[2];
    const float* tboxes = (const float*)d_in[3];

    float* out  = (float*)d_out;
    float* C    = out;                                  // 32*900*100
    float* pred = out + (size_t)BS * NQ * NT;           // 32*100
    float* tgt  = pred + BS * NT;                       // 32*100

    const size_t ctBytes = (size_t)BS * NT * NQ * sizeof(float);
    float* CT = (ws_size >= ctBytes) ? (float*)d_ws : nullptr;

    cost_kernel<<<BS * NQ, 128, 0, stream>>>(logits, boxes, tlab, tboxes, C, CT);

    if (CT) {
        float* u0 = pred;          // stash: 3200 floats, overwritten by jv epilogue
        int* amin = (int*)tgt;     // stash: 3200 ints
        rowmin_kernel<<<BS * NT, 64, 0, stream>>>(CT, u0, amin);
        jv_kernel<true ><<<BS, 64, 0, stream>>>(C, CT, u0, amin, pred, tgt);
    } else {
        jv_kernel<false><<<BS, 64, 0, stream>>>(C, nullptr, nullptr, nullptr, pred, tgt);
    }
}